// Round 2
// baseline (279.996 us; speedup 1.0000x reference)
//
#include <hip/hip_runtime.h>
#include <math.h>

// VectorQuantizer: x (32768,64) f32, codebook (8192,64) f32, start/end/use_sk ints.
// Outputs concat: x_q_st (2097152 f32) | loss (1 f32) | indices (32768 as f32 values).
//
// R11: local-window candidate records; no 16MB minima buffer; coalesced chunk eval.
//  vq_sc:    sc_k exact (pairwise-8 numpy replica, f32) + cb -> bf16 rows (K=64).
//  vq_pass1: 32x32x16 MFMA filter, block = 256 tokens x 2048 codes (quarter).
//            Per-chunk f16 minima of g(k) = -2*dot_bf(x,c_k) accumulate in LDS.
//            Epilogue per (token, quarter): local thr = local_min + WINDOW; emit
//            <=8 slots (mv_f16<<16 | chunk_id) of locally-flagged chunks (32B
//            record); >8 flagged -> slot7 = OVERFLOW (0xFFFE) and rescue evals the
//            whole quarter. Local flags SUPERSET global flags (local_min >= global
//            min), so exactness is preserved with the SAME R6-validated budget:
//            mv(k*chunk) <= min_any_slot_mv + 2*err_bf + sc_max < WINDOW.
//  vq_rescue: wave/token. thr = min over 32 slot mvs + WINDOW; candidate chunks =
//            slots with mv <= thr (~1.3/token). Per chunk: whole wave stages the
//            CONTIGUOUS 8KB of cb rows coalesced into padded LDS (the R10 killer
//            was 32-lane scattered row gathers: ~550 lines/eval in the TA), then
//            2 lanes/code evaluate with the BIT-EXACT R1 numpy-replica arithmetic
//            (j=0..3 / j=4..7 split; tt = s03+s47 via shfl_xor(.,1) -- IEEE add
//            commutative -> bit-identical both lanes). lex-min (enc(d),k).
// DO NOT change the exact-path arithmetic: inter-code d gaps are ~1 ulp of d.

#define N_E    8192
#define EDIM   64
#define NTOK   32768
#define NELEM  (NTOK * EDIM)
#define CSZ    32                  // chunk size
#define WINDOW 3e-4f
#define TTOK   256                 // pass-1 tokens per block
#define TCODE  2048                // pass-1 codes per block (16 iters of 128)
#define SROW   72                  // Cs stride (ushorts; 36 dwords == 4 mod 8)
#define MROW   76                  // minL stride (ushorts; 38 dwords, 8B-aligned rows)

typedef __attribute__((ext_vector_type(8)))  short          short8;
typedef __attribute__((ext_vector_type(8)))  unsigned short ushort8v;
typedef __attribute__((ext_vector_type(16))) float          f32x16;

__device__ __forceinline__ unsigned short f2bf(float f) {   // RTNE f32->bf16 bits
  unsigned int u = __float_as_uint(f);
  return (unsigned short)((u + 0x7FFFu + ((u >> 16) & 1u)) >> 16);
}
__device__ __forceinline__ unsigned short f2h(float f) {
  union { _Float16 h; unsigned short u; } cv; cv.h = (_Float16)f; return cv.u;
}
__device__ __forceinline__ float h2f(unsigned short b) {
  union { _Float16 h; unsigned short u; } cv; cv.u = b; return (float)cv.h;
}
__device__ __forceinline__ float max16(const f32x16 a) {
  float m0 = fmaxf(fmaxf(a[0], a[1]),   fmaxf(a[2], a[3]));
  float m1 = fmaxf(fmaxf(a[4], a[5]),   fmaxf(a[6], a[7]));
  float m2 = fmaxf(fmaxf(a[8], a[9]),   fmaxf(a[10], a[11]));
  float m3 = fmaxf(fmaxf(a[12], a[13]), fmaxf(a[14], a[15]));
  return fmaxf(fmaxf(m0, m1), fmaxf(m2, m3));
}

// ---------------- sc (exact pairwise-8) + cb -> bf16 rows (K=64) --------------------
__global__ __launch_bounds__(256) void vq_sc(const float* __restrict__ cb,
                                             float* __restrict__ sc,
                                             unsigned short* __restrict__ cbf) {
#pragma clang fp contract(off)
  int r = blockIdx.x * 256 + threadIdx.x;
  const float4* c4 = (const float4*)(cb + (size_t)r * EDIM);
  float a[8];
#pragma unroll
  for (int j = 0; j < 8; ++j) a[j] = 0.0f;
#pragma unroll
  for (int i = 0; i < 8; ++i) {
    float4 pA = c4[2*i], pB = c4[2*i+1];
    a[0] += pA.x * pA.x; a[1] += pA.y * pA.y; a[2] += pA.z * pA.z; a[3] += pA.w * pA.w;
    a[4] += pB.x * pB.x; a[5] += pB.y * pB.y; a[6] += pB.z * pB.z; a[7] += pB.w * pB.w;
  }
  float sval = ((a[0]+a[1]) + (a[2]+a[3])) + ((a[4]+a[5]) + (a[6]+a[7]));
  sc[r] = sval;
  unsigned short* dst = cbf + (size_t)r * EDIM;
#pragma unroll
  for (int h = 0; h < 8; ++h) {
    float4 fA = c4[2*h], fB = c4[2*h+1];
    ushort8v o = {f2bf(fA.x), f2bf(fA.y), f2bf(fA.z), f2bf(fA.w),
                  f2bf(fB.x), f2bf(fB.y), f2bf(fB.z), f2bf(fB.w)};
    *(ushort8v*)&dst[h * 8] = o;
  }
}

// ---------------- pass 1: MFMA filter -> per-(token,quarter) candidate records ------
// Frags: A[m=lane&31][k=8*(lane>>5)+j] (codes), B same (tokens),
// D: col=lane&31 (token), row=(reg&3)+8*(reg>>2)+4*(lane>>5) (code).
__global__ __launch_bounds__(256, 2) void vq_pass1(
    const float* __restrict__ x, const unsigned short* __restrict__ cbf,
    unsigned int* __restrict__ cand,
    const int* __restrict__ p_start, const int* __restrict__ p_end) {
  __shared__ unsigned short Cs[128 * SROW];     // 18432 B (reused as rec scratch)
  __shared__ unsigned short minL[TTOK * MROW];  // 38912 B
  int tid = threadIdx.x;
  int tb = blockIdx.x;    // token split [0,128)
  int cbk = blockIdx.y;   // code split  [0,4)  (the "quarter")
  int s = *p_start, e = *p_end;

  int lane = tid & 63, wv = tid >> 6;
  int half = lane >> 5, ln = lane & 31;
  int tokbase = wv * 64;

  // ---- stage first code tile: 128 rows x 8 ushort8 (linear, coalesced) ----
  const ushort8v* cg0 = (const ushort8v*)(cbf + (size_t)cbk * TCODE * EDIM);
#pragma unroll
  for (int p = 0; p < 4; ++p) {
    int idx = tid + p * 256;
    int row = idx >> 3, h = idx & 7;
    *(ushort8v*)&Cs[row * SROW + h * 8] = cg0[idx];
  }

  // ---- B fragments straight from global (fused f32 -> bf16), no LDS round-trip ----
  short8 bfr[2][4];
#pragma unroll
  for (int tg = 0; tg < 2; ++tg) {
    const float* xrow =
        x + (size_t)(tb * TTOK + tokbase + tg * 32 + ln) * EDIM + half * 8;
#pragma unroll
    for (int ks = 0; ks < 4; ++ks) {
      float4 fA = *(const float4*)(xrow + ks * 16);
      float4 fB = *(const float4*)(xrow + ks * 16 + 4);
      short8 v = {(short)f2bf(fA.x), (short)f2bf(fA.y), (short)f2bf(fA.z),
                  (short)f2bf(fA.w), (short)f2bf(fB.x), (short)f2bf(fB.y),
                  (short)f2bf(fB.z), (short)f2bf(fB.w)};
      bfr[tg][ks] = v;
    }
  }
  __syncthreads();

  for (int nb = 0; nb < 16; ++nb) {
    ushort8v creg[4];
    if (nb < 15) {                               // prefetch next tile into registers
      const ushort8v* cg =
          (const ushort8v*)(cbf + ((size_t)cbk * TCODE + (nb + 1) * 128) * EDIM);
#pragma unroll
      for (int p = 0; p < 4; ++p) creg[p] = cg[tid + p * 256];
    }
    f32x16 acc[2][4];
#pragma unroll
    for (int tg = 0; tg < 2; ++tg)
#pragma unroll
      for (int ct = 0; ct < 4; ++ct) acc[tg][ct] = (f32x16)0.0f;
#pragma unroll
    for (int ks = 0; ks < 4; ++ks)
#pragma unroll
      for (int ct = 0; ct < 4; ++ct) {
        short8 a = *(const short8*)&Cs[(ct*32 + ln) * SROW + ks*16 + half*8];
        acc[0][ct] = __builtin_amdgcn_mfma_f32_32x32x16_bf16(a, bfr[0][ks],
                                                             acc[0][ct], 0, 0, 0);
        acc[1][ct] = __builtin_amdgcn_mfma_f32_32x32x16_bf16(a, bfr[1][ks],
                                                             acc[1][ct], 0, 0, 0);
      }
    __syncthreads();                             // all Cs reads done
    if (nb < 15) {
#pragma unroll
      for (int p = 0; p < 4; ++p) {
        int idx = tid + p * 256;
        int row = idx >> 3, h = idx & 7;
        *(ushort8v*)&Cs[row * SROW + h * 8] = creg[p];
      }
    }
    // epilogue (registers + LDS only; overlaps Cs writes): per-chunk max -> f16 minima
    int cbase0 = cbk * TCODE + nb * 128;
    unsigned int hsel[4];
#pragma unroll
    for (int ct = 0; ct < 4; ++ct) {
      int c0 = cbase0 + ct * 32;
      bool full = (c0 >= s) && (c0 + 32 <= e);
      float v0, v1;
      if (full) {
        v0 = max16(acc[0][ct]);
        v1 = max16(acc[1][ct]);
      } else {
        v0 = -INFINITY; v1 = -INFINITY;
#pragma unroll
        for (int r = 0; r < 16; ++r) {
          int code = c0 + (r & 3) + 8 * (r >> 2) + 4 * half;
          if (code >= s && code < e) {
            v0 = fmaxf(v0, acc[0][ct][r]);
            v1 = fmaxf(v1, acc[1][ct][r]);
          }
        }
      }
      v0 = fmaxf(v0, __shfl_xor(v0, 32, 64));    // chunk max in f32 acc space
      v1 = fmaxf(v1, __shfl_xor(v1, 32, 64));
      float vs = half ? v1 : v0;                 // this thread's own token (tg==half)
      hsel[ct] = (unsigned int)f2h(-2.0f * vs);
    }
    uint2 pk;
    pk.x = hsel[0] | (hsel[1] << 16);
    pk.y = hsel[2] | (hsel[3] << 16);
    *(uint2*)&minL[(unsigned)tid * MROW + nb * 4] = pk;   // token==tid row, 8B write
    __syncthreads();                             // Cs writes visible before next MFMA
  }

  // ---- epilogue: per-token local window -> <=8 candidate slots (32B record) ----
  // Thread tid owns token tb*TTOK+tid (row tid of minL, self-written: no barrier).
  // Cs is dead after the loop's final barrier: reuse as rec scratch (dynamic index
  // into registers would spill -- rule: runtime-indexed arrays -> LDS).
  {
    const unsigned int* rp = (const unsigned int*)&minL[(unsigned)tid * MROW];
    float lmin = INFINITY;
#pragma unroll
    for (int j = 0; j < 32; ++j) {
      unsigned u = rp[j];
      lmin = fminf(lmin, fminf(h2f((unsigned short)(u & 0xFFFFu)),
                               h2f((unsigned short)(u >> 16))));
    }
    float thr = lmin + WINDOW;
    unsigned* rec = (unsigned*)&Cs[0] + (unsigned)tid * 8;
#pragma unroll
    for (int i = 0; i < 8; ++i) rec[i] = 0xFFFFFFFFu;
    int cnt = 0;
    for (int j = 0; j < 32; ++j) {
      unsigned u = rp[j];
      unsigned short mlo = (unsigned short)(u & 0xFFFFu);
      unsigned short mhi = (unsigned short)(u >> 16);
      if (h2f(mlo) <= thr) { if (cnt < 8) rec[cnt] = ((unsigned)mlo << 16) | (unsigned)(2*j);     cnt++; }
      if (h2f(mhi) <= thr) { if (cnt < 8) rec[cnt] = ((unsigned)mhi << 16) | (unsigned)(2*j + 1); cnt++; }
    }
    if (cnt > 8) rec[7] = 0x0000FFFEu;           // OVERFLOW marker (cid=0xFFFE)
    int token = tb * TTOK + tid;
    uint4* dst = (uint4*)(cand + ((size_t)token * 4 + cbk) * 8);
    dst[0] = *(const uint4*)&rec[0];
    dst[1] = *(const uint4*)&rec[4];
  }
}

// ---------------- pass 2: candidate-record exact rescue + epilogue ------------------
// Wave per token. thr = min over 32 slot mvs + WINDOW; for each surviving chunk the
// WHOLE WAVE stages the contiguous 8KB of cb rows coalesced into padded LDS, then
// 2 lanes/code evaluate with the BIT-EXACT R1 numpy-replica arithmetic.
__global__ __launch_bounds__(256, 4) void vq_rescue(
    const float* __restrict__ x, const float* __restrict__ cb,
    const float* __restrict__ sc, const unsigned int* __restrict__ cand,
    float* __restrict__ out_xq, float* __restrict__ out_idx,
    float* __restrict__ partial,
    const int* __restrict__ p_start, const int* __restrict__ p_end) {
#pragma clang fp contract(off)
  __shared__ float xs[4][64];
  __shared__ float4 cbuf[4][544];   // per-wave 32 rows x 17 float4 (padded: +1 f4)
  __shared__ float sdata[4];
  int tid  = threadIdx.x;
  int wv   = tid >> 6;
  int lane = tid & 63;
  int token = blockIdx.x * 4 + wv;

  float xx = x[(size_t)token * EDIM + lane];
  xs[wv][lane] = xx;                 // wave-private: no block barrier needed
  const float4* xl4 = (const float4*)xs[wv];

  // sx = np.sum(x*x) pairwise-8 replica
  float a[8];
#pragma unroll
  for (int j = 0; j < 8; ++j) a[j] = 0.0f;
#pragma unroll
  for (int i = 0; i < 8; ++i) {
    float4 pA = xl4[2*i], pB = xl4[2*i+1];
    a[0] += pA.x * pA.x; a[1] += pA.y * pA.y; a[2] += pA.z * pA.z; a[3] += pA.w * pA.w;
    a[4] += pB.x * pB.x; a[5] += pB.y * pB.y; a[6] += pB.z * pB.z; a[7] += pB.w * pB.w;
  }
  float sx = ((a[0]+a[1]) + (a[2]+a[3])) + ((a[4]+a[5]) + (a[6]+a[7]));

  // slots: lane<32 holds record slot (quarter=lane>>3, slot=lane&7)
  unsigned rv = 0xFFFFFFFFu;
  if (lane < 32) rv = cand[(size_t)token * 32 + lane];
  unsigned cid = rv & 0xFFFFu;
  float mvf = (cid < 64u) ? h2f((unsigned short)(rv >> 16)) : INFINITY;
  float m = mvf;
#pragma unroll
  for (int off = 32; off >= 1; off >>= 1) m = fminf(m, __shfl_xor(m, off, 64));
  float thr = m + WINDOW;

  int s = *p_start, e = *p_end;
  int mychunk = (lane >> 3) * 64 + (int)cid;     // global chunk id of my slot
  unsigned long long bal  = __ballot((lane < 32) && (cid < 64u) && (mvf <= thr));
  unsigned long long obal = __ballot((lane < 32) && (cid == 0xFFFEu));

  unsigned long long bestpack = ~0ull;
  float4* wb = cbuf[wv];
  int c = lane >> 1, h5 = lane & 1;              // lane pair per code: j 0-3 / 4-7

#define EVAL_CHUNK(CH) do {                                                    \
    const float4* src = (const float4*)(cb + (size_t)(CH) * (CSZ * EDIM));     \
    _Pragma("unroll")                                                          \
    for (int p = 0; p < 8; ++p) {                                              \
      int q = lane + p * 64;                                                   \
      wb[(q >> 4) * 17 + (q & 15)] = src[q];     /* coalesced 8KB stage */     \
    }                                                                          \
    int k = (CH) * CSZ + c;                                                    \
    float t0 = 0.0f, t1 = 0.0f, t2 = 0.0f, t3 = 0.0f;                          \
    _Pragma("unroll")                                                          \
    for (int i = 0; i < 8; ++i) {                /* elements ascending i */    \
      float4 v  = wb[c * 17 + 2 * i + h5];                                     \
      float4 p4 = xl4[2 * i + h5];                                             \
      t0 += v.x * p4.x; t1 += v.y * p4.y;                                      \
      t2 += v.z * p4.z; t3 += v.w * p4.w;                                      \
    }                                                                          \
    float s2 = (t0 + t1) + (t2 + t3);            /* s03 (h5=0) / s47 (h5=1) */ \
    float tt = s2 + __shfl_xor(s2, 1, 64);       /* IEEE add commutative */    \
    if (k >= s && k < e) {                                                     \
      float d = (sx + sc[k]) - 2.0f * tt;                                      \
      unsigned int db = __float_as_uint(d);                                    \
      unsigned int en = db ^ ((unsigned int)((int)db >> 31) | 0x80000000u);    \
      unsigned long long pk = ((unsigned long long)en << 32) | (unsigned)k;    \
      if (pk < bestpack) bestpack = pk;                                        \
    }                                                                          \
  } while (0)

  while (bal) {                                  // uniform loop (~1-2 chunks/token)
    int b = __ffsll(bal) - 1; bal &= bal - 1;
    int ch = __shfl(mychunk, b, 64);
    EVAL_CHUNK(ch);
  }
  while (obal) {                                 // overflow quarter: eval all (rare)
    int b = __ffsll(obal) - 1; obal &= obal - 1;
    int q = b >> 3;
    for (int c2 = 0; c2 < 64; ++c2) {
      int ch = q * 64 + c2;
      EVAL_CHUNK(ch);
    }
  }
#undef EVAL_CHUNK

  // lex-min reduce: (d asc, k asc) == numpy first-occurrence argmin
#pragma unroll
  for (int off = 32; off >= 1; off >>= 1) {
    unsigned long long o = __shfl_xor(bestpack, off, 64);
    if (o < bestpack) bestpack = o;
  }
  int bidx = (int)(unsigned int)(bestpack & 0xFFFFFFFFull);

  float qv = cb[(size_t)bidx * EDIM + lane];
  float diff = qv - xx;                              // fl(x_q - x)
  out_xq[(size_t)token * EDIM + lane] = xx + diff;   // fl(x + fl(x_q - x))
  if (lane == 0) out_idx[token] = (float)bidx;

  float l = diff * diff;
#pragma unroll
  for (int off = 32; off >= 1; off >>= 1) l += __shfl_down(l, off, 64);
  if (lane == 0) sdata[wv] = l;
  __syncthreads();
  if (tid == 0)
    partial[blockIdx.x] = (sdata[0] + sdata[1]) + (sdata[2] + sdata[3]);
}

// ---------------- final loss reduction ----------------------------------------------
__global__ __launch_bounds__(256) void vq_loss(const float* __restrict__ partial,
                                               float* __restrict__ out_loss) {
  int tid = threadIdx.x;
  float s = 0.0f;
  for (int i = tid; i < NTOK / 4; i += 256) s += partial[i];
#pragma unroll
  for (int off = 32; off >= 1; off >>= 1) s += __shfl_down(s, off, 64);
  __shared__ float sdata[4];
  if ((tid & 63) == 0) sdata[tid >> 6] = s;
  __syncthreads();
  if (tid == 0) {
    float total = (sdata[0] + sdata[1]) + (sdata[2] + sdata[3]);
    float m = total * (1.0f / (float)NELEM);
    out_loss[0] = m + 0.25f * m;
  }
}

// ---------------- launch -------------------------------------------------------------
extern "C" void kernel_launch(void* const* d_in, const int* in_sizes, int n_in,
                              void* d_out, int out_size, void* d_ws, size_t ws_size,
                              hipStream_t stream) {
  const float* x  = (const float*)d_in[0];
  const float* cb = (const float*)d_in[1];
  const int* p_start = (const int*)d_in[2];
  const int* p_end   = (const int*)d_in[3];

  float* ws = (float*)d_ws;
  float* sc      = ws;                                            // 8192 f
  float* partial = ws + N_E;                                      // 8192 f
  unsigned short* cbf  = (unsigned short*)(ws + 2 * N_E);         // 8192*64 us (1MB)
  unsigned int*   cand = (unsigned int*)(cbf + (size_t)N_E * EDIM); // 32768*32 u32 (4MB)

  float* out      = (float*)d_out;
  float* out_xq   = out;                 // 2097152
  float* out_loss = out + NELEM;         // 1
  float* out_idx  = out + NELEM + 1;     // 32768

  vq_sc<<<N_E / 256, 256, 0, stream>>>(cb, sc, cbf);
  dim3 g1(NTOK / TTOK, N_E / TCODE);
  vq_pass1<<<g1, 256, 0, stream>>>(x, cbf, cand, p_start, p_end);
  vq_rescue<<<NTOK / 4, 256, 0, stream>>>(x, cb, sc, cand, out_xq, out_idx,
                                          partial, p_start, p_end);
  vq_loss<<<1, 256, 0, stream>>>(partial, out_loss);
}